// Round 1
// baseline (99.410 us; speedup 1.0000x reference)
//
#include <hip/hip_runtime.h>
#include <cfloat>

// Per-row argmax-keep: out[i, argmax(x[i])] = x[i, argmax(x[i])], zeros elsewhere.
// x: [ROWS, 4096] float32. One 256-thread workgroup per row.
// Each thread: 4 x float4 loads (16 elems), register argmax (strict > keeps
// first occurrence), wave shuffle-reduce, LDS merge of 4 waves, then store
// zeros with the winning element patched.

constexpr int NCOL = 4096;

__global__ __launch_bounds__(256) void rowargmax_keep(const float* __restrict__ x,
                                                      float* __restrict__ out) {
    const int row = blockIdx.x;
    const size_t base = (size_t)row * NCOL;
    const float4* __restrict__ xin = reinterpret_cast<const float4*>(x + base);
    float4* __restrict__ xout = reinterpret_cast<float4*>(out + base);
    const int tid = threadIdx.x;

    // ---- load + per-thread argmax (indices scanned in increasing order) ----
    float best = -FLT_MAX;
    int bidx = NCOL;  // sentinel larger than any valid index
#pragma unroll
    for (int i = 0; i < 4; ++i) {
        const int f4 = tid + i * 256;       // float4 slot in row
        const float4 v = xin[f4];
        const int e = f4 * 4;               // element index of v.x
        if (v.x > best) { best = v.x; bidx = e; }
        if (v.y > best) { best = v.y; bidx = e + 1; }
        if (v.z > best) { best = v.z; bidx = e + 2; }
        if (v.w > best) { best = v.w; bidx = e + 3; }
    }

    // ---- wave (64-lane) butterfly reduce: max val, tie -> smaller idx ----
#pragma unroll
    for (int off = 32; off > 0; off >>= 1) {
        const float ov = __shfl_xor(best, off, 64);
        const int   oi = __shfl_xor(bidx, off, 64);
        if (ov > best || (ov == best && oi < bidx)) { best = ov; bidx = oi; }
    }

    // ---- cross-wave merge via LDS (4 waves) ----
    __shared__ float s_val[4];
    __shared__ int   s_idx[4];
    const int wave = tid >> 6;
    const int lane = tid & 63;
    if (lane == 0) { s_val[wave] = best; s_idx[wave] = bidx; }
    __syncthreads();

    best = s_val[0];
    bidx = s_idx[0];
#pragma unroll
    for (int w = 1; w < 4; ++w) {
        const float ov = s_val[w];
        const int   oi = s_idx[w];
        if (ov > best || (ov == best && oi < bidx)) { best = ov; bidx = oi; }
    }

    // ---- store zeros, patch the winning component ----
    const int bf4 = bidx >> 2;   // winning float4 slot
    const int bc  = bidx & 3;    // component within it
#pragma unroll
    for (int i = 0; i < 4; ++i) {
        const int f4 = tid + i * 256;
        float4 o;
        o.x = (f4 == bf4 && bc == 0) ? best : 0.0f;
        o.y = (f4 == bf4 && bc == 1) ? best : 0.0f;
        o.z = (f4 == bf4 && bc == 2) ? best : 0.0f;
        o.w = (f4 == bf4 && bc == 3) ? best : 0.0f;
        xout[f4] = o;
    }
}

extern "C" void kernel_launch(void* const* d_in, const int* in_sizes, int n_in,
                              void* d_out, int out_size, void* d_ws, size_t ws_size,
                              hipStream_t stream) {
    const float* x = (const float*)d_in[0];
    float* out = (float*)d_out;
    const int rows = in_sizes[0] / NCOL;   // 16384
    rowargmax_keep<<<rows, 256, 0, stream>>>(x, out);
}

// Round 2
// 70.190 us; speedup vs baseline: 1.4163x; 1.4163x over previous
//
#include <hip/hip_runtime.h>
#include <cfloat>

// Per-row argmax-keep: out[i, argmax(x[i])] = x[i, argmax(x[i])], zeros elsewhere.
// x: [16384, 4096] float32.
// One 64-lane WAVE per row (no LDS, no __syncthreads): each lane scans 16
// float4 (64 floats), wave butterfly-reduce (max val, tie -> smaller idx),
// then each lane streams out its 16 zero-float4s with the winner patched.
// Output uses non-temporal stores (never re-read; skip L2 allocate).

constexpr int NCOL = 4096;
constexpr int F4_PER_ROW = NCOL / 4;     // 1024
constexpr int F4_PER_LANE = F4_PER_ROW / 64;  // 16

typedef float vfloat4 __attribute__((ext_vector_type(4)));

__global__ __launch_bounds__(256) void rowargmax_keep(const float* __restrict__ x,
                                                      float* __restrict__ out) {
    const int wave_id = (blockIdx.x << 2) | (threadIdx.x >> 6);  // global wave = row
    const int lane = threadIdx.x & 63;
    const size_t base = (size_t)wave_id * NCOL;
    const vfloat4* __restrict__ xin = reinterpret_cast<const vfloat4*>(x + base);
    vfloat4* __restrict__ xout = reinterpret_cast<vfloat4*>(out + base);

    // ---- per-lane scan, increasing index order, strict > keeps first max ----
    float best = -FLT_MAX;
    int bidx = NCOL;  // sentinel
#pragma unroll
    for (int i = 0; i < F4_PER_LANE; ++i) {
        const int f4 = lane + i * 64;
        const vfloat4 v = xin[f4];
        const int e = f4 * 4;
        if (v.x > best) { best = v.x; bidx = e; }
        if (v.y > best) { best = v.y; bidx = e + 1; }
        if (v.z > best) { best = v.z; bidx = e + 2; }
        if (v.w > best) { best = v.w; bidx = e + 3; }
    }

    // ---- 64-lane butterfly reduce: max val, tie -> smaller idx ----
#pragma unroll
    for (int off = 32; off > 0; off >>= 1) {
        const float ov = __shfl_xor(best, off, 64);
        const int   oi = __shfl_xor(bidx, off, 64);
        if (ov > best || (ov == best && oi < bidx)) { best = ov; bidx = oi; }
    }

    // ---- store zeros, patch the winning component ----
    const int bf4 = bidx >> 2;
    const int bc  = bidx & 3;
#pragma unroll
    for (int i = 0; i < F4_PER_LANE; ++i) {
        const int f4 = lane + i * 64;
        vfloat4 o = (vfloat4)(0.0f);
        if (f4 == bf4) o[bc] = best;
        __builtin_nontemporal_store(o, &xout[f4]);
    }
}

extern "C" void kernel_launch(void* const* d_in, const int* in_sizes, int n_in,
                              void* d_out, int out_size, void* d_ws, size_t ws_size,
                              hipStream_t stream) {
    const float* x = (const float*)d_in[0];
    float* out = (float*)d_out;
    const int rows = in_sizes[0] / NCOL;       // 16384
    const int blocks = rows / 4;               // 4 waves (rows) per 256-thr block
    rowargmax_keep<<<blocks, 256, 0, stream>>>(x, out);
}

// Round 3
// 70.096 us; speedup vs baseline: 1.4182x; 1.0013x over previous
//
#include <hip/hip_runtime.h>
#include <cfloat>

// Per-row argmax-keep: out[i, argmax(x[i])] = x[i, argmax(x[i])], zeros elsewhere.
// x: [16384, 4096] float32. One 64-lane wave per row, no LDS/barriers.
//
// L3-residency management: input is 268 MB vs 256 MiB Infinity Cache — a
// near-fit stream that thrashes to ~50% hit rate (measured FETCH = 134 MB).
// Partition: rows [0, CACHED_ROWS) use normal loads (192 MB, stays resident
// across graph replays); rows [CACHED_ROWS, 16384) use non-temporal loads
// (64 MB, never allocates, never evicts the resident set). Output stores are
// non-temporal (write-only stream, keep it out of L3).

constexpr int NCOL = 4096;
constexpr int F4_PER_LANE = (NCOL / 4) / 64;  // 16 float4 per lane
constexpr int CACHED_ROWS = 12288;            // 12288 * 16 KB = 192 MB < 256 MB L3

typedef float vfloat4 __attribute__((ext_vector_type(4)));

template <bool NT>
__device__ inline void scan_row(const vfloat4* __restrict__ xin, int lane,
                                float& best, int& bidx) {
#pragma unroll
    for (int i = 0; i < F4_PER_LANE; ++i) {
        const int f4 = lane + i * 64;
        const vfloat4 v = NT ? __builtin_nontemporal_load(xin + f4) : xin[f4];
        const int e = f4 * 4;
        if (v.x > best) { best = v.x; bidx = e; }
        if (v.y > best) { best = v.y; bidx = e + 1; }
        if (v.z > best) { best = v.z; bidx = e + 2; }
        if (v.w > best) { best = v.w; bidx = e + 3; }
    }
}

__global__ __launch_bounds__(256) void rowargmax_keep(const float* __restrict__ x,
                                                      float* __restrict__ out) {
    const int row = (blockIdx.x << 2) | (threadIdx.x >> 6);  // global wave = row
    const int lane = threadIdx.x & 63;
    const size_t base = (size_t)row * NCOL;
    const vfloat4* __restrict__ xin = reinterpret_cast<const vfloat4*>(x + base);
    vfloat4* __restrict__ xout = reinterpret_cast<vfloat4*>(out + base);

    // ---- per-lane scan (increasing index, strict > keeps first occurrence) ----
    float best = -FLT_MAX;
    int bidx = NCOL;  // sentinel
    if (row < CACHED_ROWS) {
        scan_row<false>(xin, lane, best, bidx);
    } else {
        scan_row<true>(xin, lane, best, bidx);
    }

    // ---- 64-lane butterfly reduce: max val, tie -> smaller idx ----
#pragma unroll
    for (int off = 32; off > 0; off >>= 1) {
        const float ov = __shfl_xor(best, off, 64);
        const int   oi = __shfl_xor(bidx, off, 64);
        if (ov > best || (ov == best && oi < bidx)) { best = ov; bidx = oi; }
    }

    // ---- store zeros, patch the winning component ----
    const int bf4 = bidx >> 2;
    const int bc  = bidx & 3;
#pragma unroll
    for (int i = 0; i < F4_PER_LANE; ++i) {
        const int f4 = lane + i * 64;
        vfloat4 o = (vfloat4)(0.0f);
        if (f4 == bf4) o[bc] = best;
        __builtin_nontemporal_store(o, &xout[f4]);
    }
}

extern "C" void kernel_launch(void* const* d_in, const int* in_sizes, int n_in,
                              void* d_out, int out_size, void* d_ws, size_t ws_size,
                              hipStream_t stream) {
    const float* x = (const float*)d_in[0];
    float* out = (float*)d_out;
    const int rows = in_sizes[0] / NCOL;   // 16384
    const int blocks = rows / 4;           // 4 waves (rows) per 256-thread block
    rowargmax_keep<<<blocks, 256, 0, stream>>>(x, out);
}